// Round 3
// baseline (669.456 us; speedup 1.0000x reference)
//
#include <hip/hip_runtime.h>

typedef _Float16 f16;
typedef __attribute__((ext_vector_type(8))) _Float16 f16x8;
typedef __attribute__((ext_vector_type(8))) short s16x8;
typedef __attribute__((ext_vector_type(4))) float f32x4;

#define DIN   1024
#define DD    128
#define NBAT  4
#define TLEN  4096

// ---------- scalar conversions ----------
static __device__ __forceinline__ unsigned short f2bf(float f) {
  unsigned int u = __builtin_bit_cast(unsigned int, f);
  u = (u + 0x7fffu + ((u >> 16) & 1u)) >> 16;
  return (unsigned short)u;
}
static __device__ __forceinline__ float bf2f(unsigned short h) {
  return __builtin_bit_cast(float, (unsigned int)h << 16);
}
static __device__ __forceinline__ unsigned short f2h(float f) {
  _Float16 h = (_Float16)f;
  return __builtin_bit_cast(unsigned short, h);
}

// =====================================================================
// Kernel 1: W' = bf16 hi/lo of [Wq|Wk|Wv]^T, plain layout [col 0..383][DIN].
// =====================================================================
__global__ void build_wt(const float* __restrict__ Wq, const float* __restrict__ Wk,
                         const float* __restrict__ Wv,
                         unsigned short* __restrict__ Wh, unsigned short* __restrict__ Wl) {
  int col = blockIdx.x;                 // 0..383
  const float* W = (col < 128) ? Wq : (col < 256 ? Wk : Wv);
  int j = col & 127;
  for (int kk = (int)threadIdx.x; kk < DIN; kk += blockDim.x) {
    float w = W[(size_t)kk * DD + j];
    unsigned short h = f2bf(w);
    unsigned short l = f2bf(w - bf2f(h));
    Wh[(size_t)col * DIN + kk] = h;
    Wl[(size_t)col * DIN + kk] = l;
  }
}

// =====================================================================
// Kernel 2: projection GEMM C[16384][384] = x @ W' (bf16 hi/lo 3-product).
// 32-row x 384-col block, 4 waves, NO LDS staging / NO barriers in K-loop:
// A fragments read+converted from x directly, B fragments direct from W'
// (L2-resident, full-64B-line coalesced). q,k stored plain [t][d] f16;
// v stored transposed [n][d][t] f16 via small LDS transpose.
// =====================================================================
__global__ __launch_bounds__(256, 2) void proj_qkv(
    const float* __restrict__ x,
    const unsigned short* __restrict__ Wh, const unsigned short* __restrict__ Wl,
    unsigned short* __restrict__ qws, unsigned short* __restrict__ kws,
    unsigned short* __restrict__ vws) {
  __shared__ __align__(16) unsigned short vt[128 * 40];   // [d][t-local], stride 40 (bank spread)

  const int tid = (int)threadIdx.x;
  const int lane = tid & 63;
  const int wid = tid >> 6;
  const int t0 = blockIdx.x * 32;       // 512 blocks
  const int mf = wid >> 1;              // row half (16 rows)
  const int cf0 = (wid & 1) * 12;       // col-frag base (of 24)
  const int lrow = mf * 16 + (lane & 15);
  const int ksl = (lane >> 4) * 8;

  f32x4 acc[12];
#pragma unroll
  for (int i = 0; i < 12; ++i) acc[i] = f32x4{0.f, 0.f, 0.f, 0.f};

  const float* xrow = x + (size_t)(t0 + lrow) * DIN + ksl;

  for (int kc = 0; kc < 32; ++kc) {
    f32x4 a0 = *(const f32x4*)(xrow + kc * 32);
    f32x4 a1 = *(const f32x4*)(xrow + kc * 32 + 4);
    s16x8 ah, al;
#pragma unroll
    for (int e = 0; e < 4; ++e) {
      unsigned short h0 = f2bf(a0[e]);
      ah[e] = (short)h0;
      al[e] = (short)f2bf(a0[e] - bf2f(h0));
      unsigned short h1 = f2bf(a1[e]);
      ah[4 + e] = (short)h1;
      al[4 + e] = (short)f2bf(a1[e] - bf2f(h1));
    }
#pragma unroll
    for (int cf = 0; cf < 12; ++cf) {
      size_t off = (size_t)((cf0 + cf) * 16 + (lane & 15)) * DIN + (size_t)kc * 32 + ksl;
      s16x8 bh = *(const s16x8*)(Wh + off);
      s16x8 bl = *(const s16x8*)(Wl + off);
      acc[cf] = __builtin_amdgcn_mfma_f32_16x16x32_bf16(ah, bh, acc[cf], 0, 0, 0);
      acc[cf] = __builtin_amdgcn_mfma_f32_16x16x32_bf16(ah, bl, acc[cf], 0, 0, 0);
      acc[cf] = __builtin_amdgcn_mfma_f32_16x16x32_bf16(al, bh, acc[cf], 0, 0, 0);
    }
  }

  const int n = t0 >> 12, t0l = t0 & (TLEN - 1);
#pragma unroll
  for (int cf = 0; cf < 12; ++cf) {
    int c = (cf0 + cf) * 16 + (lane & 15);
#pragma unroll
    for (int e = 0; e < 4; ++e) {
      int tl = mf * 16 + (lane >> 4) * 4 + e;    // 0..31
      unsigned short hv = f2h(acc[cf][e]);
      if (c < 128) {
        qws[(size_t)(t0 + tl) * DD + c] = hv;
      } else if (c < 256) {
        kws[(size_t)(t0 + tl) * DD + (c - 128)] = hv;
      } else {
        vt[(c - 256) * 40 + tl] = hv;
      }
    }
  }
  __syncthreads();
  if (tid < 128) {
    int d = tid;
    unsigned short* dst = vws + ((size_t)n * DD + d) * TLEN + t0l;
#pragma unroll
    for (int h = 0; h < 4; ++h) {
      f16x8 vv = *(const f16x8*)&vt[d * 40 + h * 8];
      *(f16x8*)(dst + h * 8) = vv;
    }
  }
}

// =====================================================================
// Kernel 3: fused causal attention. 16-row q-tiles, 1024 blocks, 4 waves.
// Cost-balanced block->tile mapping (compute ~ qi, zero-fill ~ 255-qi).
// Phase A: Z row-sums via direct-global k fragments (no barriers).
// Phase B: recompute s bitwise-identically, p (= exp*rz, i.e. ALREADY
// normalized) -> LDS (XOR-swizzled, double-buffered, 1 barrier/tile),
// vectorized fp32 att stores, PV with direct-global v fragments.
// Epilogue stores oacc directly (p was normalized; NO second rz multiply).
// =====================================================================
__global__ __launch_bounds__(256, 4) void attn_fused(
    const unsigned short* __restrict__ qws, const unsigned short* __restrict__ kws,
    const unsigned short* __restrict__ vws, float* __restrict__ out,
    float* __restrict__ att) {
  __shared__ __align__(16) unsigned short pb[2][16 * 128];
  __shared__ float zbuf[4][16];
  __shared__ float rzbuf[16];

  const int tid = (int)threadIdx.x;
  const int lane = tid & 63;
  const int wid = tid >> 6;

  // balanced mapping: cost rank cr, blocks b and b+256/512/768 on one CU sum const
  int b = (int)blockIdx.x;                       // 0..1023
  int cr = (b < 512) ? (2 * b) : (2 * (1023 - b) + 1);
  const int qi = cr >> 2;                        // 0..255
  const int n = cr & 3;
  const int t0 = qi * 16;
  const int c0w = wid * 32;                      // wave's 32-col slice of the 128-col tile
  const int rl0 = (lane >> 4) * 4;               // local C-frag row base
  const int ksl = (lane >> 4) * 8;

  const unsigned short* kbase = kws + (size_t)n * TLEN * DD;
  const unsigned short* vbase = vws + (size_t)n * DD * TLEN;

  // q A-fragments: direct global loads
  f16x8 qa[4];
  {
    const unsigned short* q0 = qws + (size_t)(n * TLEN + t0 + (lane & 15)) * DD + ksl;
#pragma unroll
    for (int kc = 0; kc < 4; ++kc) qa[kc] = *(const f16x8*)(q0 + kc * 32);
  }
  const int jmax = (t0 + 15) >> 7;

  // ================= Phase A: row sums Z (no barriers) =================
  float zacc[4] = {0.f, 0.f, 0.f, 0.f};
  for (int j = 0; j <= jmax; ++j) {
    f32x4 s0 = f32x4{0.f, 0.f, 0.f, 0.f};
    f32x4 s1 = f32x4{0.f, 0.f, 0.f, 0.f};
    const unsigned short* kt = kbase + (size_t)(j * 128 + c0w + (lane & 15)) * DD + ksl;
#pragma unroll
    for (int kc = 0; kc < 4; ++kc) {
      f16x8 kb0 = *(const f16x8*)(kt + kc * 32);
      f16x8 kb1 = *(const f16x8*)(kt + 16 * DD + kc * 32);
      s0 = __builtin_amdgcn_mfma_f32_16x16x32_f16(qa[kc], kb0, s0, 0, 0, 0);
      s1 = __builtin_amdgcn_mfma_f32_16x16x32_f16(qa[kc], kb1, s1, 0, 0, 0);
    }
    int colg0 = j * 128 + c0w + (lane & 15);
#pragma unroll
    for (int e = 0; e < 4; ++e) {
      int rowg = t0 + rl0 + e;
      float ev0 = (colg0 <= rowg && s0[e] != 0.0f) ? __expf(s0[e]) : 0.0f;
      float ev1 = (colg0 + 16 <= rowg && s1[e] != 0.0f) ? __expf(s1[e]) : 0.0f;
      zacc[e] += ev0 + ev1;
    }
  }
  // reduce Z across 16 cols (lane&15), then across 4 waves via LDS
#pragma unroll
  for (int e = 0; e < 4; ++e) {
    float z = zacc[e];
    z += __shfl_xor(z, 1);
    z += __shfl_xor(z, 2);
    z += __shfl_xor(z, 4);
    z += __shfl_xor(z, 8);
    if ((lane & 15) == 0) zbuf[wid][rl0 + e] = z;
  }
  __syncthreads();
  if (tid < 16) {
    float z = zbuf[0][tid] + zbuf[1][tid] + zbuf[2][tid] + zbuf[3][tid];
    rzbuf[tid] = (z > 0.f) ? (1.0f / z) : 0.0f;
  }
  __syncthreads();
  float rz[4];
#pragma unroll
  for (int e = 0; e < 4; ++e) rz[e] = rzbuf[rl0 + e];

  // ================= Phase B =================
  f32x4 oacc0 = f32x4{0.f, 0.f, 0.f, 0.f};
  f32x4 oacc1 = f32x4{0.f, 0.f, 0.f, 0.f};
  float* attn_base = att + (size_t)n * TLEN * TLEN + (size_t)t0 * TLEN;
  int cur = 0;

  for (int j = 0; j <= jmax; ++j) {
    // recompute s (bitwise identical to phase A)
    f32x4 s0 = f32x4{0.f, 0.f, 0.f, 0.f};
    f32x4 s1 = f32x4{0.f, 0.f, 0.f, 0.f};
    const unsigned short* kt = kbase + (size_t)(j * 128 + c0w + (lane & 15)) * DD + ksl;
#pragma unroll
    for (int kc = 0; kc < 4; ++kc) {
      f16x8 kb0 = *(const f16x8*)(kt + kc * 32);
      f16x8 kb1 = *(const f16x8*)(kt + 16 * DD + kc * 32);
      s0 = __builtin_amdgcn_mfma_f32_16x16x32_f16(qa[kc], kb0, s0, 0, 0, 0);
      s1 = __builtin_amdgcn_mfma_f32_16x16x32_f16(qa[kc], kb1, s1, 0, 0, 0);
    }
    unsigned short* pw = pb[cur];
    int colg0 = j * 128 + c0w + (lane & 15);
#pragma unroll
    for (int e = 0; e < 4; ++e) {
      int rowg = t0 + rl0 + e;
      int rl = rl0 + e;
      float ev0 = (colg0 <= rowg && s0[e] != 0.0f) ? __expf(s0[e]) : 0.0f;
      float ev1 = (colg0 + 16 <= rowg && s1[e] != 0.0f) ? __expf(s1[e]) : 0.0f;
      int c0 = c0w + (lane & 15);
      int c1 = c0 + 16;
      pw[rl * 128 + ((((c0 >> 3) ^ (rl & 7)) << 3) | (c0 & 7))] = f2h(ev0 * rz[e]);
      pw[rl * 128 + ((((c1 >> 3) ^ (rl & 7)) << 3) | (c1 & 7))] = f2h(ev1 * rz[e]);
    }
    __syncthreads();

    // vectorized att store: 16 rows x 128 cols fp32, 32B/thread contiguous
    {
      int r = tid >> 4, c8 = tid & 15;
      f16x8 pv = *(const f16x8*)&pw[r * 128 + (((c8 ^ (r & 7)) & 15) << 3)];
      f32x4 o0, o1;
#pragma unroll
      for (int i = 0; i < 4; ++i) {
        o0[i] = (float)pv[i];
        o1[i] = (float)pv[4 + i];
      }
      float* dst = attn_base + (size_t)r * TLEN + j * 128 + c8 * 8;
      *(f32x4*)dst = o0;
      *(f32x4*)(dst + 4) = o1;
    }

    // PV: out += p @ v, v fragments direct from global (v is [n][d][t])
#pragma unroll
    for (int kc = 0; kc < 4; ++kc) {
      int rp = lane & 15;
      f16x8 pa = *(const f16x8*)&pw[rp * 128 + ((((kc * 4 + (lane >> 4)) ^ (rp & 7)) & 15) << 3)];
      const unsigned short* vt0 = vbase + (size_t)(c0w + (lane & 15)) * TLEN + (size_t)j * 128 + kc * 32 + ksl;
      f16x8 vb0 = *(const f16x8*)(vt0);
      f16x8 vb1 = *(const f16x8*)(vt0 + (size_t)16 * TLEN);
      oacc0 = __builtin_amdgcn_mfma_f32_16x16x32_f16(pa, vb0, oacc0, 0, 0, 0);
      oacc1 = __builtin_amdgcn_mfma_f32_16x16x32_f16(pa, vb1, oacc1, 0, 0, 0);
    }
    cur ^= 1;
  }

  // ---- out store (p was already normalized by rz inside the PV input) ----
#pragma unroll
  for (int e = 0; e < 4; ++e) {
    int t = t0 + rl0 + e;
    float* orow = out + ((size_t)n * TLEN + t) * DD;
    orow[c0w + (lane & 15)] = oacc0[e];
    orow[c0w + 16 + (lane & 15)] = oacc1[e];
  }

  // ---- zero-fill strictly-upper region ----
  int cz0 = (jmax + 1) * 128;
  f32x4 zv = f32x4{0.f, 0.f, 0.f, 0.f};
  for (int r = 0; r < 16; ++r) {
    float* rowp = attn_base + (size_t)r * TLEN;
    for (int c = cz0 + tid * 4; c < TLEN; c += 1024) {
      *(f32x4*)(rowp + c) = zv;
    }
  }
}

// =====================================================================
extern "C" void kernel_launch(void* const* d_in, const int* in_sizes, int n_in,
                              void* d_out, int out_size, void* d_ws, size_t ws_size,
                              hipStream_t stream) {
  const float* x  = (const float*)d_in[0];
  const float* Wq = (const float*)d_in[1];
  const float* Wk = (const float*)d_in[2];
  const float* Wv = (const float*)d_in[3];

  float* out = (float*)d_out;                              // [4,4096,128]
  float* att = out + (size_t)NBAT * TLEN * DD;             // [4,4096,4096]

  unsigned short* ws = (unsigned short*)d_ws;
  unsigned short* Wh  = ws;                                // 384*1024
  unsigned short* Wl  = Wh + (size_t)384 * DIN;
  unsigned short* qws = Wl + (size_t)384 * DIN;            // 16384*128 f16 [t][d]
  unsigned short* kws = qws + (size_t)NBAT * TLEN * DD;    // 16384*128 f16 [t][d]
  unsigned short* vws = kws + (size_t)NBAT * TLEN * DD;    // [4][128][4096] f16

  build_wt<<<dim3(384), dim3(256), 0, stream>>>(Wq, Wk, Wv, Wh, Wl);
  proj_qkv<<<dim3(512), dim3(256), 0, stream>>>(x, Wh, Wl, qws, kws, vws);
  attn_fused<<<dim3(1024), dim3(256), 0, stream>>>(qws, kws, vws, out, att);
}

// Round 4
// 532.381 us; speedup vs baseline: 1.2575x; 1.2575x over previous
//
#include <hip/hip_runtime.h>

typedef _Float16 f16;
typedef __attribute__((ext_vector_type(8))) _Float16 f16x8;
typedef __attribute__((ext_vector_type(8))) short s16x8;
typedef __attribute__((ext_vector_type(4))) float f32x4;

#define DIN   1024
#define DD    128
#define NBAT  4
#define TLEN  4096

// ---------- scalar conversions ----------
static __device__ __forceinline__ unsigned short f2bf(float f) {
  unsigned int u = __builtin_bit_cast(unsigned int, f);
  u = (u + 0x7fffu + ((u >> 16) & 1u)) >> 16;
  return (unsigned short)u;
}
static __device__ __forceinline__ float bf2f(unsigned short h) {
  return __builtin_bit_cast(float, (unsigned int)h << 16);
}
static __device__ __forceinline__ unsigned short f2h(float f) {
  _Float16 h = (_Float16)f;
  return __builtin_bit_cast(unsigned short, h);
}
// 128-elem row swizzle: 16B granules XORed by key (bank-conflict-free LDS reads)
static __device__ __forceinline__ int swz128(int d, int key) {
  return ((((d >> 3) ^ key) & 15) << 3) | (d & 7);
}

// ---------- async global->LDS, width 16 ----------
typedef __attribute__((address_space(1))) const unsigned int* gas1_t;
typedef __attribute__((address_space(3))) unsigned int* las3_t;
static __device__ __forceinline__ void gload16(const void* g, void* l) {
  __builtin_amdgcn_global_load_lds((gas1_t)g, (las3_t)l, 16, 0, 0);
}

// =====================================================================
// Kernel 0: x fp32 -> bf16 hi/lo (one pass, memory-bound)
// =====================================================================
__global__ void xcast(const float* __restrict__ x,
                      unsigned short* __restrict__ xh, unsigned short* __restrict__ xl) {
  size_t i = ((size_t)blockIdx.x * 256 + threadIdx.x) * 8;
  f32x4 a0 = *(const f32x4*)(x + i);
  f32x4 a1 = *(const f32x4*)(x + i + 4);
  s16x8 hv, lv;
#pragma unroll
  for (int e = 0; e < 4; ++e) {
    unsigned short h0 = f2bf(a0[e]);
    hv[e] = (short)h0; lv[e] = (short)f2bf(a0[e] - bf2f(h0));
    unsigned short h1 = f2bf(a1[e]);
    hv[4 + e] = (short)h1; lv[4 + e] = (short)f2bf(a1[e] - bf2f(h1));
  }
  *(s16x8*)(xh + i) = hv;
  *(s16x8*)(xl + i) = lv;
}

// =====================================================================
// Kernel 1: W' = bf16 hi/lo of [Wq|Wk|Wv]^T, plain layout [col 0..383][DIN].
// =====================================================================
__global__ void build_wt(const float* __restrict__ Wq, const float* __restrict__ Wk,
                         const float* __restrict__ Wv,
                         unsigned short* __restrict__ Wh, unsigned short* __restrict__ Wl) {
  int col = blockIdx.x;                 // 0..383
  const float* W = (col < 128) ? Wq : (col < 256 ? Wk : Wv);
  int j = col & 127;
  for (int kk = (int)threadIdx.x; kk < DIN; kk += blockDim.x) {
    float w = W[(size_t)kk * DD + j];
    unsigned short h = f2bf(w);
    unsigned short l = f2bf(w - bf2f(h));
    Wh[(size_t)col * DIN + kk] = h;
    Wl[(size_t)col * DIN + kk] = l;
  }
}

// =====================================================================
// Kernel 2: projection GEMM C[16384][384] = x @ W' (bf16 hi/lo 3-product).
// 512 blocks x 32 rows; 4 waves, wave = 32 rows x 96 cols. Pure load+MFMA
// (x pre-cast). q plain [t][d]; k swizzled rows; v transposed [n][d][t-swz].
// =====================================================================
__global__ __launch_bounds__(256, 2) void proj_qkv(
    const unsigned short* __restrict__ xh, const unsigned short* __restrict__ xl,
    const unsigned short* __restrict__ Wh, const unsigned short* __restrict__ Wl,
    unsigned short* __restrict__ qws, unsigned short* __restrict__ kws,
    unsigned short* __restrict__ vws) {
  __shared__ __align__(16) unsigned short vt[128 * 40];

  const int tid = (int)threadIdx.x;
  const int lane = tid & 63;
  const int wid = tid >> 6;
  const int lr = lane & 15;
  const int lg = lane >> 4;
  const int t0 = blockIdx.x * 32;

  f32x4 acc[2][6];
#pragma unroll
  for (int a = 0; a < 2; ++a)
#pragma unroll
    for (int b = 0; b < 6; ++b) acc[a][b] = f32x4{0.f, 0.f, 0.f, 0.f};

  for (int kc = 0; kc < 32; ++kc) {
    s16x8 ah[2], al[2];
#pragma unroll
    for (int rf = 0; rf < 2; ++rf) {
      size_t aoff = (size_t)(t0 + rf * 16 + lr) * DIN + kc * 32 + lg * 8;
      ah[rf] = *(const s16x8*)(xh + aoff);
      al[rf] = *(const s16x8*)(xl + aoff);
    }
#pragma unroll
    for (int cf = 0; cf < 6; ++cf) {
      size_t boff = (size_t)(wid * 96 + cf * 16 + lr) * DIN + kc * 32 + lg * 8;
      s16x8 bh = *(const s16x8*)(Wh + boff);
      s16x8 bl = *(const s16x8*)(Wl + boff);
#pragma unroll
      for (int rf = 0; rf < 2; ++rf) {
        acc[rf][cf] = __builtin_amdgcn_mfma_f32_16x16x32_bf16(ah[rf], bh, acc[rf][cf], 0, 0, 0);
        acc[rf][cf] = __builtin_amdgcn_mfma_f32_16x16x32_bf16(ah[rf], bl, acc[rf][cf], 0, 0, 0);
        acc[rf][cf] = __builtin_amdgcn_mfma_f32_16x16x32_bf16(al[rf], bh, acc[rf][cf], 0, 0, 0);
      }
    }
  }

  const int n = t0 >> 12, t0l = t0 & (TLEN - 1);
#pragma unroll
  for (int cf = 0; cf < 6; ++cf) {
    int c = wid * 96 + cf * 16 + lr;
#pragma unroll
    for (int rf = 0; rf < 2; ++rf)
#pragma unroll
      for (int e = 0; e < 4; ++e) {
        int tl = rf * 16 + lg * 4 + e;           // 0..31
        int t = t0 + tl;
        unsigned short hv = f2h(acc[rf][cf][e]);
        if (c < 128) {
          qws[(size_t)t * DD + c] = hv;                       // plain
        } else if (c < 256) {
          kws[(size_t)t * DD + swz128(c - 128, t & 7)] = hv;  // row-swizzled
        } else {
          vt[(c - 256) * 40 + tl] = hv;
        }
      }
  }
  __syncthreads();
  if (tid < 128) {
    int d = tid;
    int ch = t0l >> 7, pos0 = t0l & 127;
    unsigned short* dst = vws + ((size_t)n * DD + d) * TLEN + ch * 128;
#pragma unroll
    for (int h = 0; h < 4; ++h) {
      f16x8 vv = *(const f16x8*)&vt[d * 40 + h * 8];
      int g = (((pos0 + h * 8) >> 3) ^ (d & 7)) << 3;
      *(f16x8*)(dst + g) = vv;
    }
  }
}

// =====================================================================
// Kernel 3: fused causal attention. 512 blocks x 512 thr (8 waves),
// 32-row q-tiles. Block b -> cr = (b<256)? b : 767-b (per-CU balance);
// each block also zero-fills its OWN rows' upper region (uniform writes).
// k/v LDS-staged (shared x8 waves); p-bounce is WAVE-PRIVATE (no barrier);
// PV = per-wave K=32 slice over all d; one cross-wave reduce at the end.
// =====================================================================
__global__ __launch_bounds__(512, 4) void attn_fused(
    const unsigned short* __restrict__ qws, const unsigned short* __restrict__ kws,
    const unsigned short* __restrict__ vws, float* __restrict__ out,
    float* __restrict__ att) {
  __shared__ __align__(16) unsigned short kvbuf[32768];   // kl 32KB | vl 32KB
  __shared__ __align__(16) unsigned short pp[8][16 * 40]; // wave-private p
  __shared__ float zb[8][16];
  __shared__ float rzb[32];
  unsigned short* kl = kvbuf;
  unsigned short* vl = kvbuf + 16384;

  const int tid = (int)threadIdx.x;
  const int lane = tid & 63;
  const int wid = tid >> 6;
  const int lr = lane & 15;
  const int lg = lane >> 4;
  const int rg = wid >> 2;              // row group (0/1): rows rg*16
  const int cg = wid & 3;               // col group: cols cg*32 of 128-tile

  int b = (int)blockIdx.x;
  int cr = (b < 256) ? b : (767 - b);
  const int qi = cr >> 2;               // 0..127
  const int n = cr & 3;
  const int t0 = qi * 32;
  const int jmax = (t0 + 31) >> 7;

  const unsigned short* kbase = kws + (size_t)(n * TLEN) * DD;
  const unsigned short* vbase = vws + (size_t)n * DD * TLEN;
  float* attn_base = att + (size_t)n * TLEN * TLEN + (size_t)t0 * TLEN;

  // ---- zero-fill this block's own upper region first (overlaps phase A) ----
  {
    int cz0 = (jmax + 1) * 128;
    f32x4 zv = f32x4{0.f, 0.f, 0.f, 0.f};
    for (int r = 0; r < 32; ++r) {
      float* rowp = attn_base + (size_t)r * TLEN;
      for (int c = cz0 + tid * 4; c < TLEN; c += 2048) *(f32x4*)(rowp + c) = zv;
    }
  }

  // ---- q A-fragments (plain layout, direct global) ----
  f16x8 qa[4];
  {
    const unsigned short* q0 = qws + (size_t)(n * TLEN + t0 + rg * 16 + lr) * DD + lg * 8;
#pragma unroll
    for (int kc = 0; kc < 4; ++kc) qa[kc] = *(const f16x8*)(q0 + kc * 32);
  }
  const int rowl0 = rg * 16 + lg * 4;   // local row base of this lane's C-frags

  // ================= Phase A: row sums Z =================
  float zacc[4] = {0.f, 0.f, 0.f, 0.f};
  for (int j = 0; j <= jmax; ++j) {
    const char* gk = (const char*)(kbase + (size_t)(j * 128) * DD);
#pragma unroll
    for (int rr = 0; rr < 4; ++rr) {
      int idx = rr * 512 + tid;         // 2048 chunks of 16B
      gload16(gk + (size_t)idx * 16, (char*)kl + (size_t)idx * 16);
    }
    __syncthreads();
#pragma unroll
    for (int cf = 0; cf < 2; ++cf) {
      int krow = cg * 32 + cf * 16 + lr;
      f32x4 s = f32x4{0.f, 0.f, 0.f, 0.f};
#pragma unroll
      for (int kc = 0; kc < 4; ++kc) {
        f16x8 kb = *(const f16x8*)&kl[krow * 128 + ((((kc * 4 + lg) ^ (krow & 7))) << 3)];
        s = __builtin_amdgcn_mfma_f32_16x16x32_f16(qa[kc], kb, s, 0, 0, 0);
      }
      int colg = j * 128 + krow;
#pragma unroll
      for (int e = 0; e < 4; ++e) {
        int rowg = t0 + rowl0 + e;
        zacc[e] += (colg <= rowg && s[e] != 0.0f) ? __expf(s[e]) : 0.0f;
      }
    }
    __syncthreads();
  }
#pragma unroll
  for (int e = 0; e < 4; ++e) {
    float z = zacc[e];
    z += __shfl_xor(z, 1);
    z += __shfl_xor(z, 2);
    z += __shfl_xor(z, 4);
    z += __shfl_xor(z, 8);
    if (lr == 0) zb[wid][lg * 4 + e] = z;
  }
  __syncthreads();
  if (tid < 32) {
    int r = tid, rgq = r >> 4, rl = r & 15;
    float z = zb[rgq * 4 + 0][rl] + zb[rgq * 4 + 1][rl] + zb[rgq * 4 + 2][rl] + zb[rgq * 4 + 3][rl];
    rzb[r] = (z > 0.f) ? (1.0f / z) : 0.0f;
  }
  __syncthreads();
  float rz[4];
#pragma unroll
  for (int e = 0; e < 4; ++e) rz[e] = rzb[rowl0 + e];

  // ================= Phase B =================
  f32x4 oacc[8];
#pragma unroll
  for (int fd = 0; fd < 8; ++fd) oacc[fd] = f32x4{0.f, 0.f, 0.f, 0.f};
  unsigned short* ppw = pp[wid];

  for (int j = 0; j <= jmax; ++j) {
    const char* gk = (const char*)(kbase + (size_t)(j * 128) * DD);
#pragma unroll
    for (int rr = 0; rr < 4; ++rr) {
      int idx = rr * 512 + tid;
      gload16(gk + (size_t)idx * 16, (char*)kl + (size_t)idx * 16);
    }
#pragma unroll
    for (int rr = 0; rr < 4; ++rr) {
      int idx = rr * 512 + tid;
      int d = idx >> 4, off = idx & 15;
      gload16((const char*)(vbase + ((size_t)d * TLEN + j * 128 + off * 8)),
              (char*)vl + (size_t)idx * 16);
    }
    __syncthreads();

    // recompute s (bitwise identical), write att + wave-private p
#pragma unroll
    for (int cf = 0; cf < 2; ++cf) {
      int krow = cg * 32 + cf * 16 + lr;
      f32x4 s = f32x4{0.f, 0.f, 0.f, 0.f};
#pragma unroll
      for (int kc = 0; kc < 4; ++kc) {
        f16x8 kb = *(const f16x8*)&kl[krow * 128 + ((((kc * 4 + lg) ^ (krow & 7))) << 3)];
        s = __builtin_amdgcn_mfma_f32_16x16x32_f16(qa[kc], kb, s, 0, 0, 0);
      }
      int colg = j * 128 + krow;
#pragma unroll
      for (int e = 0; e < 4; ++e) {
        int rowg = t0 + rowl0 + e;
        float ev = (colg <= rowg && s[e] != 0.0f) ? __expf(s[e]) : 0.0f;
        float p = ev * rz[e];
        attn_base[(size_t)(rowl0 + e) * TLEN + colg] = p;
        ppw[(lg * 4 + e) * 40 + cf * 16 + lr] = f2h(p);   // local col cf*16+lr of wave's 32
      }
    }
    // wave-synchronous p read (A-layout) — no barrier, lgkmcnt only
    f16x8 pa = *(const f16x8*)&ppw[lr * 40 + lg * 8];
    // PV: K=32 slice (this wave's cols), all 128 d
#pragma unroll
    for (int fd = 0; fd < 8; ++fd) {
      int d = fd * 16 + lr;
      f16x8 vb = *(const f16x8*)&vl[d * 128 + ((((cg * 4 + lg) ^ (d & 7))) << 3)];
      oacc[fd] = __builtin_amdgcn_mfma_f32_16x16x32_f16(pa, vb, oacc[fd], 0, 0, 0);
    }
    __syncthreads();
  }

  // ---- cross-wave PV reduction (reuse k/v LDS as 8x16x128 f32) ----
  float* red = (float*)kvbuf;
#pragma unroll
  for (int fd = 0; fd < 8; ++fd)
#pragma unroll
    for (int e = 0; e < 4; ++e)
      red[((size_t)wid * 16 + lg * 4 + e) * 128 + fd * 16 + lr] = oacc[fd][e];
  __syncthreads();
  {
    int r = tid >> 4;                   // 0..31
    int d0 = (tid & 15) * 8;
    int rgq = r >> 4, rl = r & 15;
    f32x4 s0 = f32x4{0.f, 0.f, 0.f, 0.f}, s1 = f32x4{0.f, 0.f, 0.f, 0.f};
#pragma unroll
    for (int c = 0; c < 4; ++c) {
      const float* src = red + ((size_t)(rgq * 4 + c) * 16 + rl) * 128 + d0;
      f32x4 a = *(const f32x4*)src;
      f32x4 bb = *(const f32x4*)(src + 4);
#pragma unroll
      for (int i = 0; i < 4; ++i) { s0[i] += a[i]; s1[i] += bb[i]; }
    }
    float* dst = out + ((size_t)n * TLEN + t0 + r) * DD + d0;
    *(f32x4*)dst = s0;
    *(f32x4*)(dst + 4) = s1;
  }
}

// =====================================================================
extern "C" void kernel_launch(void* const* d_in, const int* in_sizes, int n_in,
                              void* d_out, int out_size, void* d_ws, size_t ws_size,
                              hipStream_t stream) {
  const float* x  = (const float*)d_in[0];
  const float* Wq = (const float*)d_in[1];
  const float* Wk = (const float*)d_in[2];
  const float* Wv = (const float*)d_in[3];

  float* out = (float*)d_out;                              // [4,4096,128]
  float* att = out + (size_t)NBAT * TLEN * DD;             // [4,4096,4096]

  unsigned short* ws = (unsigned short*)d_ws;
  unsigned short* Wh  = ws;                                // 384*1024
  unsigned short* Wl  = Wh + (size_t)384 * DIN;
  unsigned short* xh  = Wl + (size_t)384 * DIN;            // 16384*1024
  unsigned short* xl  = xh + (size_t)NBAT * TLEN * DIN;
  unsigned short* qws = xl + (size_t)NBAT * TLEN * DIN;    // 16384*128 f16 [t][d]
  unsigned short* kws = qws + (size_t)NBAT * TLEN * DD;    // swizzled rows
  unsigned short* vws = kws + (size_t)NBAT * TLEN * DD;    // [4][128][4096] t-swz

  xcast<<<dim3(8192), dim3(256), 0, stream>>>(x, xh, xl);
  build_wt<<<dim3(384), dim3(256), 0, stream>>>(Wq, Wk, Wv, Wh, Wl);
  proj_qkv<<<dim3(512), dim3(256), 0, stream>>>(xh, xl, Wh, Wl, qws, kws, vws);
  attn_fused<<<dim3(512), dim3(512), 0, stream>>>(qws, kws, vws, out, att);
}